// Round 3
// baseline (541.458 us; speedup 1.0000x reference)
//
#include <hip/hip_runtime.h>

using u16 = unsigned short;
using u32 = unsigned int;

#define PI2 6.283185307179586f

struct cpx { float x, y; };

__device__ __forceinline__ float bf2f(u16 h){ return __uint_as_float(((u32)h) << 16); }
__device__ __forceinline__ u16 f2bf(float f){
  u32 u = __float_as_uint(f);
  u = u + 0x7fffu + ((u >> 16) & 1u);   // RNE
  return (u16)(u >> 16);
}

// mode: 0 = inputs/outputs bf16, 1 = fp32
__device__ __forceinline__ float ldv(const void* base, size_t i, int md){
  return md ? ((const float*)base)[i] : bf2f(((const u16*)base)[i]);
}

__device__ __forceinline__ cpx cadd(cpx a, cpx b){ return {a.x+b.x, a.y+b.y}; }
__device__ __forceinline__ cpx csub(cpx a, cpx b){ return {a.x-b.x, a.y-b.y}; }
__device__ __forceinline__ cpx cmul(cpx a, cpx b){ return {a.x*b.x - a.y*b.y, a.x*b.y + a.y*b.x}; }
__device__ __forceinline__ int br6(int l){ return (int)(__brev((u32)l) >> 26); }
__device__ __forceinline__ cpx shflx(cpx v, int m){
  cpx r; r.x = __shfl_xor(v.x, m, 64); r.y = __shfl_xor(v.y, m, 64); return r;
}

__device__ __forceinline__ void make_tw(int l, cpx tw[6]){
  #pragma unroll
  for (int s = 0; s < 6; s++){
    int h = 64 >> s;
    float ang = -PI2 * (float)(l & (h-1)) / (float)(2*h);
    float sv, cv; sincosf(ang, &sv, &cv);
    tw[s] = {cv, sv};
  }
}

// DIF, natural input (v0=pos l, v1=pos l+64); after float4 store at br6(l), natural order
__device__ __forceinline__ void fft_fwd(cpx& v0, cpx& v1, int l, const cpx tw[6]){
  cpx a = cadd(v0, v1), b = csub(v0, v1);
  v0 = a; v1 = cmul(b, tw[0]);
  #pragma unroll
  for (int s = 1; s < 6; s++){
    int h = 64 >> s;
    cpx p0 = shflx(v0, h), p1 = shflx(v1, h);
    bool up = (l & h) != 0;
    cpx n0 = up ? cmul(csub(p0, v0), tw[s]) : cadd(v0, p0);
    cpx n1 = up ? cmul(csub(p1, v1), tw[s]) : cadd(v1, p1);
    v0 = n0; v1 = n1;
  }
  { cpx p0 = shflx(v0, 1), p1 = shflx(v1, 1);
    bool up = (l & 1) != 0;
    v0 = up ? csub(p0, v0) : cadd(v0, p0);
    v1 = up ? csub(p1, v1) : cadd(v1, p1); }
}

// DIT, input gathered via float4 at br6(l) from natural order; unnormalized IDFT
__device__ __forceinline__ void fft_inv(cpx& v0, cpx& v1, int l, const cpx tw[6]){
  { cpx p0 = shflx(v0, 1), p1 = shflx(v1, 1);
    bool up = (l & 1) != 0;
    v0 = up ? csub(p0, v0) : cadd(v0, p0);
    v1 = up ? csub(p1, v1) : cadd(v1, p1); }
  #pragma unroll
  for (int s = 5; s >= 1; s--){
    int h = 64 >> s;
    cpx twc = {tw[s].x, -tw[s].y};
    cpx p0 = shflx(v0, h), p1 = shflx(v1, h);
    bool up = (l & h) != 0;
    cpx t0 = cmul(up ? v0 : p0, twc);
    cpx t1 = cmul(up ? v1 : p1, twc);
    v0 = up ? csub(p0, t0) : cadd(v0, t0);
    v1 = up ? csub(p1, t1) : cadd(v1, t1);
  }
  { cpx twc = {tw[0].x, -tw[0].y};
    cpx t = cmul(v1, twc);
    cpx n0 = cadd(v0, t), n1 = csub(v0, t);
    v0 = n0; v1 = n1; }
}

__device__ __forceinline__ float softplusf(float x){ return (x > 20.0f) ? x : log1pf(expf(x)); }

// ---- contiguous-row matvec helpers ----
// lane l owns elements e = [8l, 8l+8) of first row-half and 512 + [8l, 8l+8) of second half.
__device__ __forceinline__ void acc8_bf(uint4 a, uint4 b, float x0, float x1, float acc[8]){
  acc[0] = fmaf(x0, __uint_as_float(a.x << 16),         acc[0]);
  acc[1] = fmaf(x0, __uint_as_float(a.x & 0xffff0000u), acc[1]);
  acc[2] = fmaf(x0, __uint_as_float(a.y << 16),         acc[2]);
  acc[3] = fmaf(x0, __uint_as_float(a.y & 0xffff0000u), acc[3]);
  acc[4] = fmaf(x0, __uint_as_float(a.z << 16),         acc[4]);
  acc[5] = fmaf(x0, __uint_as_float(a.z & 0xffff0000u), acc[5]);
  acc[6] = fmaf(x0, __uint_as_float(a.w << 16),         acc[6]);
  acc[7] = fmaf(x0, __uint_as_float(a.w & 0xffff0000u), acc[7]);
  acc[0] = fmaf(x1, __uint_as_float(b.x << 16),         acc[0]);
  acc[1] = fmaf(x1, __uint_as_float(b.x & 0xffff0000u), acc[1]);
  acc[2] = fmaf(x1, __uint_as_float(b.y << 16),         acc[2]);
  acc[3] = fmaf(x1, __uint_as_float(b.y & 0xffff0000u), acc[3]);
  acc[4] = fmaf(x1, __uint_as_float(b.z << 16),         acc[4]);
  acc[5] = fmaf(x1, __uint_as_float(b.z & 0xffff0000u), acc[5]);
  acc[6] = fmaf(x1, __uint_as_float(b.w << 16),         acc[6]);
  acc[7] = fmaf(x1, __uint_as_float(b.w & 0xffff0000u), acc[7]);
}
__device__ __forceinline__ void acc8_f32(float4 a0, float4 a1, float4 b0, float4 b1,
                                         float x0, float x1, float acc[8]){
  acc[0] = fmaf(x0, a0.x, acc[0]); acc[1] = fmaf(x0, a0.y, acc[1]);
  acc[2] = fmaf(x0, a0.z, acc[2]); acc[3] = fmaf(x0, a0.w, acc[3]);
  acc[4] = fmaf(x0, a1.x, acc[4]); acc[5] = fmaf(x0, a1.y, acc[5]);
  acc[6] = fmaf(x0, a1.z, acc[6]); acc[7] = fmaf(x0, a1.w, acc[7]);
  acc[0] = fmaf(x1, b0.x, acc[0]); acc[1] = fmaf(x1, b0.y, acc[1]);
  acc[2] = fmaf(x1, b0.z, acc[2]); acc[3] = fmaf(x1, b0.w, acc[3]);
  acc[4] = fmaf(x1, b1.x, acc[4]); acc[5] = fmaf(x1, b1.y, acc[5]);
  acc[6] = fmaf(x1, b1.z, acc[6]); acc[7] = fmaf(x1, b1.w, acc[7]);
}

// ---- K_DETECT: sample g1 as bf16; fp32 low-halves look huge/NaN -> mode 1 ----
__global__ void k_detect(const void* g1, int* flag){
  __shared__ int cnt;
  if (threadIdx.x == 0) cnt = 0;
  __syncthreads();
  const u16* p = (const u16*)g1;
  int local = 0;
  for (int i = threadIdx.x; i < 4096; i += 256){
    float v = bf2f(p[i]);
    if (!(fabsf(v) < 100.0f)) local++;   // counts NaN/inf too
  }
  atomicAdd(&cnt, local);
  __syncthreads();
  if (threadIdx.x == 0) *flag = (cnt > 64) ? 1 : 0;
}

// ---- K0: softplus tables: [amp_Gs, k0_Gs, amp_G, k0_G], 1024 fp32 each ----
__global__ void k_tabs(const void* k0G, const void* ampG, const void* k0Gs, const void* ampGs,
                       float* tabs, const int* flag){
  int md = *flag;
  for (int i = threadIdx.x; i < 1024; i += 256){
    tabs[i]        = softplusf(ldv(ampGs, i, md));
    tabs[1024 + i] = softplusf(ldv(k0Gs, i, md));
    tabs[2048 + i] = softplusf(ldv(ampG, i, md));
    tabs[3072 + i] = softplusf(ldv(k0G, i, md));
  }
}

// ---- K1: per-pixel MLP s = project(k) -> S[b][h][j][c] fp32 ----
__global__ __launch_bounds__(256) void k_project(const void* kin, const void* W1, const void* b1,
    const void* W2, const void* b2, const void* W3, const void* b3, float* S, const int* flag){
  __shared__ float sW2[1024], sW3[1024], sml[128];
  int md = *flag;
  int t = threadIdx.x;
  for (int i = t; i < 1024; i += 256){ sW2[i] = ldv(W2, i, md); sW3[i] = ldv(W3, i, md); }
  if (t < 32){
    sml[t]     = ldv(W1, t, md); sml[32+t] = ldv(b1, t, md);
    sml[64+t]  = ldv(b2, t, md); sml[96+t] = ldv(b3, t, md);
  }
  __syncthreads();
  int pix = blockIdx.x * 256 + t;
  float kv = ldv(kin, pix, md);
  float a1[32], a2[32];
  #pragma unroll
  for (int c = 0; c < 32; c++){ float z = fmaf(kv, sml[c], sml[32+c]); a1[c] = expf(-z*z); }
  for (int o = 0; o < 32; o++){
    float z = sml[64+o];
    #pragma unroll
    for (int c = 0; c < 32; c++) z = fmaf(a1[c], sW2[c*32+o], z);
    a2[o] = expf(-z*z);
  }
  for (int o = 0; o < 32; o++){
    float sv = sml[96+o];
    #pragma unroll
    for (int c = 0; c < 32; c++) sv = fmaf(a2[c], sW3[c*32+o], sv);
    S[(size_t)pix*32 + o] = sv;
  }
}

// ---- K2: Du = _D(g2, u) ; persistent waves, 2 pixels/iter, 1-deep prefetch ----
__global__ __launch_bounds__(256) void k_dmat(const void* u, const void* g2, float* D, const int* flag){
  int md = *flag;
  int t = threadIdx.x, l = t & 63;
  int wid = blockIdx.x * 4 + (t >> 6);       // 0..4095, 8 pixels each
  size_t base = (size_t)wid * 8;
  int c32 = l & 31, ch = l >> 2;
  const u16* U16 = (const u16*)u;
  const float* U32 = (const float*)u;
  if (!md){
    const uint4* R = (const uint4*)((const u16*)g2 + base*1024);
    uint4 a0 = R[l], a1 = R[64+l], b0 = R[128+l], b1 = R[192+l];
    float xa = bf2f(U16[base*32 + c32]);
    float xb = bf2f(U16[(base+1)*32 + c32]);
    #pragma unroll
    for (int it = 0; it < 4; it++){
      int nit = (it < 3) ? it + 1 : it;
      uint4 na0 = R[nit*256 + l],       na1 = R[nit*256 + 64 + l];
      uint4 nb0 = R[nit*256 + 128 + l], nb1 = R[nit*256 + 192 + l];
      float nxa = bf2f(U16[(base + 2*nit)*32 + c32]);
      float nxb = bf2f(U16[(base + 2*nit + 1)*32 + c32]);
      float xa0 = __shfl(xa, ch, 64), xa1 = __shfl(xa, 16+ch, 64);
      float xb0 = __shfl(xb, ch, 64), xb1 = __shfl(xb, 16+ch, 64);
      float acc0[8] = {0.f,0.f,0.f,0.f,0.f,0.f,0.f,0.f};
      float acc1[8] = {0.f,0.f,0.f,0.f,0.f,0.f,0.f,0.f};
      acc8_bf(a0, a1, xa0, xa1, acc0);
      acc8_bf(b0, b1, xb0, xb1, acc1);
      #pragma unroll
      for (int d = 4; d <= 32; d <<= 1){
        #pragma unroll
        for (int jj = 0; jj < 8; jj++){
          acc0[jj] += __shfl_xor(acc0[jj], d, 64);
          acc1[jj] += __shfl_xor(acc1[jj], d, 64);
        }
      }
      size_t p0 = base + 2*it, p1 = p0 + 1;
      if (l < 4){
        ((float4*)(D + p0*32))[2*l]   = make_float4(acc0[0], acc0[1], acc0[2], acc0[3]);
        ((float4*)(D + p0*32))[2*l+1] = make_float4(acc0[4], acc0[5], acc0[6], acc0[7]);
        ((float4*)(D + p1*32))[2*l]   = make_float4(acc1[0], acc1[1], acc1[2], acc1[3]);
        ((float4*)(D + p1*32))[2*l+1] = make_float4(acc1[4], acc1[5], acc1[6], acc1[7]);
      }
      a0 = na0; a1 = na1; b0 = nb0; b1 = nb1; xa = nxa; xb = nxb;
    }
  } else {
    const float4* R = (const float4*)((const float*)g2 + base*1024);
    float4 a0 = R[2*l], a1 = R[2*l+1], a2 = R[128+2*l], a3 = R[128+2*l+1];
    float4 b0 = R[256+2*l], b1 = R[256+2*l+1], b2 = R[384+2*l], b3 = R[384+2*l+1];
    float xa = U32[base*32 + c32];
    float xb = U32[(base+1)*32 + c32];
    #pragma unroll
    for (int it = 0; it < 4; it++){
      int nit = (it < 3) ? it + 1 : it;
      const float4* Rn = R + nit*512;
      float4 na0 = Rn[2*l], na1 = Rn[2*l+1], na2 = Rn[128+2*l], na3 = Rn[128+2*l+1];
      float4 nb0 = Rn[256+2*l], nb1 = Rn[256+2*l+1], nb2 = Rn[384+2*l], nb3 = Rn[384+2*l+1];
      float nxa = U32[(base + 2*nit)*32 + c32];
      float nxb = U32[(base + 2*nit + 1)*32 + c32];
      float xa0 = __shfl(xa, ch, 64), xa1 = __shfl(xa, 16+ch, 64);
      float xb0 = __shfl(xb, ch, 64), xb1 = __shfl(xb, 16+ch, 64);
      float acc0[8] = {0.f,0.f,0.f,0.f,0.f,0.f,0.f,0.f};
      float acc1[8] = {0.f,0.f,0.f,0.f,0.f,0.f,0.f,0.f};
      acc8_f32(a0, a1, a2, a3, xa0, xa1, acc0);
      acc8_f32(b0, b1, b2, b3, xb0, xb1, acc1);
      #pragma unroll
      for (int d = 4; d <= 32; d <<= 1){
        #pragma unroll
        for (int jj = 0; jj < 8; jj++){
          acc0[jj] += __shfl_xor(acc0[jj], d, 64);
          acc1[jj] += __shfl_xor(acc1[jj], d, 64);
        }
      }
      size_t p0 = base + 2*it, p1 = p0 + 1;
      if (l < 4){
        ((float4*)(D + p0*32))[2*l]   = make_float4(acc0[0], acc0[1], acc0[2], acc0[3]);
        ((float4*)(D + p0*32))[2*l+1] = make_float4(acc0[4], acc0[5], acc0[6], acc0[7]);
        ((float4*)(D + p1*32))[2*l]   = make_float4(acc1[0], acc1[1], acc1[2], acc1[3]);
        ((float4*)(D + p1*32))[2*l+1] = make_float4(acc1[4], acc1[5], acc1[6], acc1[7]);
      }
      a0 = na0; a1 = na1; a2 = na2; a3 = na3;
      b0 = nb0; b1 = nb1; b2 = nb2; b3 = nb3;
      xa = nxa; xb = nxb;
    }
  }
}

// ---- KG_A: per (p, j): B-combine + H-FFT + channel mix + H-IFFT ; 512 threads ----
__global__ __launch_bounds__(512) void kg_a(const float* S, const float* Dd, const float* tabs, float2* Q){
  __shared__ __align__(16) cpx E[64*128];   // 64 KB
  int t = threadIdx.x;
  int p = blockIdx.x >> 7, j = blockIdx.x & 127;
  const float* X = p ? Dd : S;
  const float* ampT = tabs + p*2048;
  const float* k0T  = ampT + 1024;
  int l = t & 63, w = t >> 6;               // w in [0,8)
  cpx tw[6]; make_tw(l, tw);

  // stage + combine over B: col c = (x0+x1) (B-freq 0), col 32+c = (x0-x1) (B-freq 1)
  {
    int h = t >> 2, ch = (t & 3) * 8;
    const float4* x0 = (const float4*)(X + (((size_t)h)*128 + j)*32 + ch);
    const float4* x1 = (const float4*)(X + (((size_t)(128 + h))*128 + j)*32 + ch);
    #pragma unroll
    for (int q = 0; q < 2; q++){
      float4 A = x0[q], B = x1[q];
      int c = ch + q*4;
      E[(c+0)*128 + h] = {A.x+B.x, 0.f};  E[(32+c+0)*128 + h] = {A.x-B.x, 0.f};
      E[(c+1)*128 + h] = {A.y+B.y, 0.f};  E[(32+c+1)*128 + h] = {A.y-B.y, 0.f};
      E[(c+2)*128 + h] = {A.z+B.z, 0.f};  E[(32+c+2)*128 + h] = {A.z-B.z, 0.f};
      E[(c+3)*128 + h] = {A.w+B.w, 0.f};  E[(32+c+3)*128 + h] = {A.w-B.w, 0.f};
    }
  }
  __syncthreads();
  // forward FFT over h for all 64 columns (bit-reversal folded into float4 store)
  for (int c = w; c < 64; c += 8){
    cpx* col = E + c*128;
    cpx v0 = col[l], v1 = col[l+64];
    fft_fwd(v0, v1, l, tw);
    ((float4*)col)[br6(l)] = make_float4(v0.x, v0.y, v1.x, v1.y);
  }
  __syncthreads();
  // mix: Y[b][o][i] = sum_c E[b][c][i] * G(c,o,i,j); G shared across b
  {
    int o = t & 31, ig = t >> 5;            // ig in [0,16)
    float aT[32], kT[32];
    #pragma unroll
    for (int c = 0; c < 32; c++){ aT[c] = ampT[c*32+o]; kT[c] = k0T[c*32+o]; }
    float fj = (j < 64) ? (float)j : (float)(j - 128);
    fj *= (PI2 / 128.0f);
    float px = fj * fj;
    for (int chunk = 0; chunk < 2; chunk++){
      cpx y0[4], y1[4];
      #pragma unroll
      for (int q = 0; q < 4; q++){
        int i = ig + 16*(chunk*4 + q);
        float fi = (i < 64) ? (float)i : (float)(i - 128);
        fi *= (PI2 / 128.0f);
        float pp = fmaf(fi, fi, px);
        cpx a0 = {0.f, 0.f}, a1 = {0.f, 0.f};
        #pragma unroll
        for (int c = 0; c < 32; c++){
          float dd  = fmaf(aT[c], pp, -kT[c]);
          float inv = __builtin_amdgcn_rcpf(fmaf(dd, dd, 1.0f));  // ~1ulp, << bf16 tol
          float gr = dd * inv, gi = inv;      // 1/(d - i) = (d + i)/(d^2+1)
          cpx x0 = E[c*128 + i];
          cpx x1 = E[(32+c)*128 + i];
          a0.x = fmaf(x0.x, gr, fmaf(-x0.y, gi, a0.x));
          a0.y = fmaf(x0.x, gi, fmaf( x0.y, gr, a0.y));
          a1.x = fmaf(x1.x, gr, fmaf(-x1.y, gi, a1.x));
          a1.y = fmaf(x1.x, gi, fmaf( x1.y, gr, a1.y));
        }
        y0[q] = a0; y1[q] = a1;
      }
      __syncthreads();
      #pragma unroll
      for (int q = 0; q < 4; q++){
        int i = ig + 16*(chunk*4 + q);
        E[o*128 + i]      = y0[q];
        E[(32+o)*128 + i] = y1[q];
      }
      __syncthreads();
    }
  }
  // inverse FFT over i for 64 (b,o) columns, scale 1/128
  for (int cidx = w; cidx < 64; cidx += 8){
    cpx* col = E + cidx*128;
    float4 tv = ((const float4*)col)[br6(l)];
    cpx v0 = {tv.x, tv.y}, v1 = {tv.z, tv.w};
    fft_inv(v0, v1, l, tw);
    const float sc = 1.0f/128.0f;
    col[l]    = {v0.x*sc, v0.y*sc};
    col[l+64] = {v1.x*sc, v1.y*sc};
  }
  __syncthreads();
  // writeout Q[p][b][y][j][o]
  {
    int o = t & 31, bb = (t >> 5) & 1, yb = t >> 6;   // yb in [0,8)
    for (int m = 0; m < 16; m++){
      int y = yb + 8*m;
      cpx v = E[(bb*32+o)*128 + y];
      Q[((((size_t)(p*2+bb))*128 + y)*128 + j)*32 + o] = make_float2(v.x, v.y);
    }
  }
}

// ---- KG_C: per (p, b, y): IFFT over W (natural input), real part -> G0/G1 [b][y][j][c] ----
// LDS strides padded: Z stride 130 cpx (16B-aligned cols, breaks 16-way write conflicts),
// R stride 133 floats (writeout gather conflict-free: 5*c4 mod 32 distinct for c4=0,4,..,28)
#define ZS 130
#define RS 133
__global__ __launch_bounds__(256) void kg_c(const float2* Q, float* G0, float* G1){
  __shared__ __align__(16) cpx Z[32*ZS];
  __shared__ float R[32*RS];
  int t = threadIdx.x, l = t & 63, w = t >> 6;
  int idx = blockIdx.x;
  int p = idx >> 8, rem = idx & 255, bb = rem >> 7, y = rem & 127;
  cpx tw[6]; make_tw(l, tw);
  const float4* src = (const float4*)(Q + ((size_t)((p*2+bb)*128 + y))*4096);
  for (int q = t; q < 2048; q += 256){
    float4 v = src[q];
    int m = q*2, jj = m >> 5, c = m & 31;
    Z[c*ZS + jj]     = {v.x, v.y};
    Z[(c+1)*ZS + jj] = {v.z, v.w};
  }
  __syncthreads();
  for (int c = w; c < 32; c += 4){
    cpx* col = Z + c*ZS;
    float4 tv = ((const float4*)col)[br6(l)];
    cpx v0 = {tv.x, tv.y}, v1 = {tv.z, tv.w};
    fft_inv(v0, v1, l, tw);
    R[c*RS + l]      = v0.x * (1.0f/128.0f);
    R[c*RS + l + 64] = v1.x * (1.0f/128.0f);
  }
  __syncthreads();
  float* dst = (p ? G1 : G0) + ((size_t)(bb*128 + y))*4096;
  int jj = t >> 3, c4 = (t & 7)*4;
  for (int rep = 0; rep < 4; rep++){
    int j2 = jj + rep*32;
    float4 o4 = { R[(c4+0)*RS + j2], R[(c4+1)*RS + j2],
                  R[(c4+2)*RS + j2], R[(c4+3)*RS + j2] };
    ((float4*)(dst + (size_t)j2*32))[c4 >> 2] = o4;
  }
}

// ---- K3: out = _D(g4,Gs) + _D(g1,Gm) + _D(g3,u) ; persistent waves, 1-deep prefetch ----
__global__ __launch_bounds__(256) void k_final(const void* u, const void* g1, const void* g3, const void* g4,
    const float* G0, const float* G1, void* out, const int* flag){
  int md = *flag;
  int t = threadIdx.x, l = t & 63;
  int wid = blockIdx.x * 4 + (t >> 6);       // 0..8191, 4 pixels each
  size_t base = (size_t)wid * 4;
  int c32 = l & 31, ch = l >> 2;
  if (!md){
    const u16* U = (const u16*)u;
    const uint4* R4 = (const uint4*)((const u16*)g4 + base*1024);
    const uint4* R1 = (const uint4*)((const u16*)g1 + base*1024);
    const uint4* R3 = (const uint4*)((const u16*)g3 + base*1024);
    uint4 a4 = R4[l], b4 = R4[64+l];
    uint4 a1 = R1[l], b1 = R1[64+l];
    uint4 a3 = R3[l], b3 = R3[64+l];
    float xs = G0[base*32 + c32], xm = G1[base*32 + c32], xu = bf2f(U[base*32 + c32]);
    #pragma unroll
    for (int it = 0; it < 4; it++){
      int nit = (it < 3) ? it + 1 : it;
      uint4 na4 = R4[nit*128 + l], nb4 = R4[nit*128 + 64 + l];
      uint4 na1 = R1[nit*128 + l], nb1 = R1[nit*128 + 64 + l];
      uint4 na3 = R3[nit*128 + l], nb3 = R3[nit*128 + 64 + l];
      float nxs = G0[(base+nit)*32 + c32];
      float nxm = G1[(base+nit)*32 + c32];
      float nxu = bf2f(U[(base+nit)*32 + c32]);
      float xs0 = __shfl(xs, ch, 64), xs1 = __shfl(xs, 16+ch, 64);
      float xm0 = __shfl(xm, ch, 64), xm1 = __shfl(xm, 16+ch, 64);
      float xu0 = __shfl(xu, ch, 64), xu1 = __shfl(xu, 16+ch, 64);
      float acc[8] = {0.f,0.f,0.f,0.f,0.f,0.f,0.f,0.f};
      acc8_bf(a4, b4, xs0, xs1, acc);
      acc8_bf(a1, b1, xm0, xm1, acc);
      acc8_bf(a3, b3, xu0, xu1, acc);
      #pragma unroll
      for (int d = 4; d <= 32; d <<= 1){
        #pragma unroll
        for (int jj = 0; jj < 8; jj++) acc[jj] += __shfl_xor(acc[jj], d, 64);
      }
      size_t pix = base + it;
      if (l < 4){
        uint4 v;
        v.x = (u32)f2bf(acc[0]) | ((u32)f2bf(acc[1]) << 16);
        v.y = (u32)f2bf(acc[2]) | ((u32)f2bf(acc[3]) << 16);
        v.z = (u32)f2bf(acc[4]) | ((u32)f2bf(acc[5]) << 16);
        v.w = (u32)f2bf(acc[6]) | ((u32)f2bf(acc[7]) << 16);
        ((uint4*)out)[pix*4 + l] = v;
      }
      a4 = na4; b4 = nb4; a1 = na1; b1 = nb1; a3 = na3; b3 = nb3;
      xs = nxs; xm = nxm; xu = nxu;
    }
  } else {
    const float* U = (const float*)u;
    const float4* R4 = (const float4*)((const float*)g4 + base*1024);
    const float4* R1 = (const float4*)((const float*)g1 + base*1024);
    const float4* R3 = (const float4*)((const float*)g3 + base*1024);
    float4 p4a = R4[2*l], p4b = R4[2*l+1], q4a = R4[128+2*l], q4b = R4[128+2*l+1];
    float4 p1a = R1[2*l], p1b = R1[2*l+1], q1a = R1[128+2*l], q1b = R1[128+2*l+1];
    float4 p3a = R3[2*l], p3b = R3[2*l+1], q3a = R3[128+2*l], q3b = R3[128+2*l+1];
    float xs = G0[base*32 + c32], xm = G1[base*32 + c32], xu = U[base*32 + c32];
    #pragma unroll
    for (int it = 0; it < 4; it++){
      int nit = (it < 3) ? it + 1 : it;
      const float4* R4n = R4 + nit*256;
      const float4* R1n = R1 + nit*256;
      const float4* R3n = R3 + nit*256;
      float4 n4a = R4n[2*l], n4b = R4n[2*l+1], m4a = R4n[128+2*l], m4b = R4n[128+2*l+1];
      float4 n1a = R1n[2*l], n1b = R1n[2*l+1], m1a = R1n[128+2*l], m1b = R1n[128+2*l+1];
      float4 n3a = R3n[2*l], n3b = R3n[2*l+1], m3a = R3n[128+2*l], m3b = R3n[128+2*l+1];
      float nxs = G0[(base+nit)*32 + c32];
      float nxm = G1[(base+nit)*32 + c32];
      float nxu = U[(base+nit)*32 + c32];
      float xs0 = __shfl(xs, ch, 64), xs1 = __shfl(xs, 16+ch, 64);
      float xm0 = __shfl(xm, ch, 64), xm1 = __shfl(xm, 16+ch, 64);
      float xu0 = __shfl(xu, ch, 64), xu1 = __shfl(xu, 16+ch, 64);
      float acc[8] = {0.f,0.f,0.f,0.f,0.f,0.f,0.f,0.f};
      acc8_f32(p4a, p4b, q4a, q4b, xs0, xs1, acc);
      acc8_f32(p1a, p1b, q1a, q1b, xm0, xm1, acc);
      acc8_f32(p3a, p3b, q3a, q3b, xu0, xu1, acc);
      #pragma unroll
      for (int d = 4; d <= 32; d <<= 1){
        #pragma unroll
        for (int jj = 0; jj < 8; jj++) acc[jj] += __shfl_xor(acc[jj], d, 64);
      }
      size_t pix = base + it;
      if (l < 4){
        float4 o0 = {acc[0], acc[1], acc[2], acc[3]};
        float4 o1 = {acc[4], acc[5], acc[6], acc[7]};
        ((float4*)out)[pix*8 + 2*l]     = o0;
        ((float4*)out)[pix*8 + 2*l + 1] = o1;
      }
      p4a = n4a; p4b = n4b; q4a = m4a; q4b = m4b;
      p1a = n1a; p1b = n1b; q1a = m1a; q1b = m1b;
      p3a = n3a; p3b = n3b; q3a = m3a; q3b = m3b;
      xs = nxs; xm = nxm; xu = nxu;
    }
  }
}

extern "C" void kernel_launch(void* const* d_in, const int* in_sizes, int n_in,
                              void* d_out, int out_size, void* d_ws, size_t ws_size,
                              hipStream_t stream){
  (void)in_sizes; (void)n_in; (void)out_size; (void)ws_size;
  const void* u    = d_in[0];
  const void* kk   = d_in[1];
  const void* g1   = d_in[2];
  const void* g2   = d_in[3];
  const void* g3   = d_in[4];
  const void* g4   = d_in[5];
  const void* W1   = d_in[6];
  const void* b1   = d_in[7];
  const void* W2   = d_in[8];
  const void* b2   = d_in[9];
  const void* W3   = d_in[10];
  const void* b3   = d_in[11];
  const void* k0G  = d_in[12];
  const void* ampG = d_in[13];
  const void* k0Gs = d_in[14];
  const void* ampGs= d_in[15];

  float* ws   = (float*)d_ws;
  float* S    = ws;                          // 1M fp32
  float* Dd   = ws + (1u<<20);               // 1M fp32
  float2* Q   = (float2*)(ws + 2*(1u<<20));  // 2M cplx (4M fp32)
  float* G0   = ws + 6*(1u<<20);             // 1M fp32
  float* G1b  = ws + 7*(1u<<20);             // 1M fp32
  float* tabs = ws + 8*(1u<<20);             // 4K fp32
  int*   flag = (int*)(tabs + 4096);

  k_detect <<<1,    256, 0, stream>>>(g1, flag);
  k_tabs   <<<1,    256, 0, stream>>>(k0G, ampG, k0Gs, ampGs, tabs, flag);
  k_project<<<128,  256, 0, stream>>>(kk, W1, b1, W2, b2, W3, b3, S, flag);
  k_dmat   <<<1024, 256, 0, stream>>>(u, g2, Dd, flag);
  kg_a     <<<256,  512, 0, stream>>>(S, Dd, tabs, Q);
  kg_c     <<<512,  256, 0, stream>>>(Q, G0, G1b);
  k_final  <<<2048, 256, 0, stream>>>(u, g1, g3, g4, G0, G1b, (void*)d_out, flag);
}

// Round 4
// 538.930 us; speedup vs baseline: 1.0047x; 1.0047x over previous
//
#include <hip/hip_runtime.h>

using u16 = unsigned short;
using u32 = unsigned int;

#define PI2 6.283185307179586f

struct cpx { float x, y; };

typedef unsigned int uvec4 __attribute__((ext_vector_type(4)));
typedef float fvec4 __attribute__((ext_vector_type(4)));

__device__ __forceinline__ uint4 ldnt_u4(const uint4* p){
  uvec4 v = __builtin_nontemporal_load((const uvec4*)p);
  uint4 r; r.x = v.x; r.y = v.y; r.z = v.z; r.w = v.w; return r;
}
__device__ __forceinline__ float4 ldnt_f4(const float4* p){
  fvec4 v = __builtin_nontemporal_load((const fvec4*)p);
  float4 r; r.x = v.x; r.y = v.y; r.z = v.z; r.w = v.w; return r;
}

__device__ __forceinline__ float bf2f(u16 h){ return __uint_as_float(((u32)h) << 16); }
__device__ __forceinline__ u16 f2bf(float f){
  u32 u = __float_as_uint(f);
  u = u + 0x7fffu + ((u >> 16) & 1u);   // RNE
  return (u16)(u >> 16);
}

// mode: 0 = inputs/outputs bf16, 1 = fp32
__device__ __forceinline__ float ldv(const void* base, size_t i, int md){
  return md ? ((const float*)base)[i] : bf2f(((const u16*)base)[i]);
}

__device__ __forceinline__ cpx cadd(cpx a, cpx b){ return {a.x+b.x, a.y+b.y}; }
__device__ __forceinline__ cpx csub(cpx a, cpx b){ return {a.x-b.x, a.y-b.y}; }
__device__ __forceinline__ cpx cmul(cpx a, cpx b){ return {a.x*b.x - a.y*b.y, a.x*b.y + a.y*b.x}; }
__device__ __forceinline__ int br6(int l){ return (int)(__brev((u32)l) >> 26); }
__device__ __forceinline__ cpx shflx(cpx v, int m){
  cpx r; r.x = __shfl_xor(v.x, m, 64); r.y = __shfl_xor(v.y, m, 64); return r;
}

__device__ __forceinline__ void make_tw(int l, cpx tw[6]){
  #pragma unroll
  for (int s = 0; s < 6; s++){
    int h = 64 >> s;
    float ang = -PI2 * (float)(l & (h-1)) / (float)(2*h);
    float sv, cv; sincosf(ang, &sv, &cv);
    tw[s] = {cv, sv};
  }
}

// DIF, natural input (v0=pos l, v1=pos l+64); after float4 store at br6(l), natural order
__device__ __forceinline__ void fft_fwd(cpx& v0, cpx& v1, int l, const cpx tw[6]){
  cpx a = cadd(v0, v1), b = csub(v0, v1);
  v0 = a; v1 = cmul(b, tw[0]);
  #pragma unroll
  for (int s = 1; s < 6; s++){
    int h = 64 >> s;
    cpx p0 = shflx(v0, h), p1 = shflx(v1, h);
    bool up = (l & h) != 0;
    cpx n0 = up ? cmul(csub(p0, v0), tw[s]) : cadd(v0, p0);
    cpx n1 = up ? cmul(csub(p1, v1), tw[s]) : cadd(v1, p1);
    v0 = n0; v1 = n1;
  }
  { cpx p0 = shflx(v0, 1), p1 = shflx(v1, 1);
    bool up = (l & 1) != 0;
    v0 = up ? csub(p0, v0) : cadd(v0, p0);
    v1 = up ? csub(p1, v1) : cadd(v1, p1); }
}

// DIT, input gathered via float4 at br6(l) from natural order; unnormalized IDFT
__device__ __forceinline__ void fft_inv(cpx& v0, cpx& v1, int l, const cpx tw[6]){
  { cpx p0 = shflx(v0, 1), p1 = shflx(v1, 1);
    bool up = (l & 1) != 0;
    v0 = up ? csub(p0, v0) : cadd(v0, p0);
    v1 = up ? csub(p1, v1) : cadd(v1, p1); }
  #pragma unroll
  for (int s = 5; s >= 1; s--){
    int h = 64 >> s;
    cpx twc = {tw[s].x, -tw[s].y};
    cpx p0 = shflx(v0, h), p1 = shflx(v1, h);
    bool up = (l & h) != 0;
    cpx t0 = cmul(up ? v0 : p0, twc);
    cpx t1 = cmul(up ? v1 : p1, twc);
    v0 = up ? csub(p0, t0) : cadd(v0, t0);
    v1 = up ? csub(p1, t1) : cadd(v1, t1);
  }
  { cpx twc = {tw[0].x, -tw[0].y};
    cpx t = cmul(v1, twc);
    cpx n0 = cadd(v0, t), n1 = csub(v0, t);
    v0 = n0; v1 = n1; }
}

__device__ __forceinline__ float softplusf(float x){ return (x > 20.0f) ? x : log1pf(expf(x)); }

// ---- contiguous-row matvec helpers ----
// lane l owns elements e = [8l, 8l+8) of first row-half and 512 + [8l, 8l+8) of second half.
__device__ __forceinline__ void acc8_bf(uint4 a, uint4 b, float x0, float x1, float acc[8]){
  acc[0] = fmaf(x0, __uint_as_float(a.x << 16),         acc[0]);
  acc[1] = fmaf(x0, __uint_as_float(a.x & 0xffff0000u), acc[1]);
  acc[2] = fmaf(x0, __uint_as_float(a.y << 16),         acc[2]);
  acc[3] = fmaf(x0, __uint_as_float(a.y & 0xffff0000u), acc[3]);
  acc[4] = fmaf(x0, __uint_as_float(a.z << 16),         acc[4]);
  acc[5] = fmaf(x0, __uint_as_float(a.z & 0xffff0000u), acc[5]);
  acc[6] = fmaf(x0, __uint_as_float(a.w << 16),         acc[6]);
  acc[7] = fmaf(x0, __uint_as_float(a.w & 0xffff0000u), acc[7]);
  acc[0] = fmaf(x1, __uint_as_float(b.x << 16),         acc[0]);
  acc[1] = fmaf(x1, __uint_as_float(b.x & 0xffff0000u), acc[1]);
  acc[2] = fmaf(x1, __uint_as_float(b.y << 16),         acc[2]);
  acc[3] = fmaf(x1, __uint_as_float(b.y & 0xffff0000u), acc[3]);
  acc[4] = fmaf(x1, __uint_as_float(b.z << 16),         acc[4]);
  acc[5] = fmaf(x1, __uint_as_float(b.z & 0xffff0000u), acc[5]);
  acc[6] = fmaf(x1, __uint_as_float(b.w << 16),         acc[6]);
  acc[7] = fmaf(x1, __uint_as_float(b.w & 0xffff0000u), acc[7]);
}
__device__ __forceinline__ void acc8_f32(float4 a0, float4 a1, float4 b0, float4 b1,
                                         float x0, float x1, float acc[8]){
  acc[0] = fmaf(x0, a0.x, acc[0]); acc[1] = fmaf(x0, a0.y, acc[1]);
  acc[2] = fmaf(x0, a0.z, acc[2]); acc[3] = fmaf(x0, a0.w, acc[3]);
  acc[4] = fmaf(x0, a1.x, acc[4]); acc[5] = fmaf(x0, a1.y, acc[5]);
  acc[6] = fmaf(x0, a1.z, acc[6]); acc[7] = fmaf(x0, a1.w, acc[7]);
  acc[0] = fmaf(x1, b0.x, acc[0]); acc[1] = fmaf(x1, b0.y, acc[1]);
  acc[2] = fmaf(x1, b0.z, acc[2]); acc[3] = fmaf(x1, b0.w, acc[3]);
  acc[4] = fmaf(x1, b1.x, acc[4]); acc[5] = fmaf(x1, b1.y, acc[5]);
  acc[6] = fmaf(x1, b1.z, acc[6]); acc[7] = fmaf(x1, b1.w, acc[7]);
}

// ---- K_DETECT: sample g1 as bf16; fp32 low-halves look huge/NaN -> mode 1 ----
__global__ void k_detect(const void* g1, int* flag){
  __shared__ int cnt;
  if (threadIdx.x == 0) cnt = 0;
  __syncthreads();
  const u16* p = (const u16*)g1;
  int local = 0;
  for (int i = threadIdx.x; i < 4096; i += 256){
    float v = bf2f(p[i]);
    if (!(fabsf(v) < 100.0f)) local++;   // counts NaN/inf too
  }
  atomicAdd(&cnt, local);
  __syncthreads();
  if (threadIdx.x == 0) *flag = (cnt > 64) ? 1 : 0;
}

// ---- K0: softplus tables: [amp_Gs, k0_Gs, amp_G, k0_G], 1024 fp32 each ----
__global__ void k_tabs(const void* k0G, const void* ampG, const void* k0Gs, const void* ampGs,
                       float* tabs, const int* flag){
  int md = *flag;
  for (int i = threadIdx.x; i < 1024; i += 256){
    tabs[i]        = softplusf(ldv(ampGs, i, md));
    tabs[1024 + i] = softplusf(ldv(k0Gs, i, md));
    tabs[2048 + i] = softplusf(ldv(ampG, i, md));
    tabs[3072 + i] = softplusf(ldv(k0G, i, md));
  }
}

// ---- K1: per-pixel MLP s = project(k) -> S[b][h][j][c] fp32 ----
__global__ __launch_bounds__(256) void k_project(const void* kin, const void* W1, const void* b1,
    const void* W2, const void* b2, const void* W3, const void* b3, float* S, const int* flag){
  __shared__ float sW2[1024], sW3[1024], sml[128];
  int md = *flag;
  int t = threadIdx.x;
  for (int i = t; i < 1024; i += 256){ sW2[i] = ldv(W2, i, md); sW3[i] = ldv(W3, i, md); }
  if (t < 32){
    sml[t]     = ldv(W1, t, md); sml[32+t] = ldv(b1, t, md);
    sml[64+t]  = ldv(b2, t, md); sml[96+t] = ldv(b3, t, md);
  }
  __syncthreads();
  int pix = blockIdx.x * 256 + t;
  float kv = ldv(kin, pix, md);
  float a1[32], a2[32];
  #pragma unroll
  for (int c = 0; c < 32; c++){ float z = fmaf(kv, sml[c], sml[32+c]); a1[c] = expf(-z*z); }
  for (int o = 0; o < 32; o++){
    float z = sml[64+o];
    #pragma unroll
    for (int c = 0; c < 32; c++) z = fmaf(a1[c], sW2[c*32+o], z);
    a2[o] = expf(-z*z);
  }
  for (int o = 0; o < 32; o++){
    float sv = sml[96+o];
    #pragma unroll
    for (int c = 0; c < 32; c++) sv = fmaf(a2[c], sW3[c*32+o], sv);
    S[(size_t)pix*32 + o] = sv;
  }
}

// ---- K2: Du = _D(g2, u) -> fp32 ; 1 wave = 2 pixels, NT streaming g2 reads ----
__global__ __launch_bounds__(256) void k_dmat(const void* u, const void* g2, float* D, const int* flag){
  int md = *flag;
  int t = threadIdx.x, l = t & 63;
  size_t pix = (size_t)blockIdx.x * 8 + (size_t)(t >> 6) * 2;
  int c32 = l & 31, ch = l >> 2;
  float xa = ldv(u, pix*32 + c32, md);
  float xb = ldv(u, (pix+1)*32 + c32, md);
  float acc0[8] = {0.f,0.f,0.f,0.f,0.f,0.f,0.f,0.f};
  float acc1[8] = {0.f,0.f,0.f,0.f,0.f,0.f,0.f,0.f};
  if (md){
    const float4* Ra = (const float4*)((const float*)g2 + pix*1024);
    const float4* Rb = (const float4*)((const float*)g2 + (pix+1)*1024);
    float4 aa = ldnt_f4(Ra+2*l), ab = ldnt_f4(Ra+2*l+1), ac = ldnt_f4(Ra+128+2*l), ad = ldnt_f4(Ra+128+2*l+1);
    float4 ba = ldnt_f4(Rb+2*l), bb = ldnt_f4(Rb+2*l+1), bc = ldnt_f4(Rb+128+2*l), bd = ldnt_f4(Rb+128+2*l+1);
    float xa0 = __shfl(xa, ch, 64), xa1 = __shfl(xa, 16+ch, 64);
    float xb0 = __shfl(xb, ch, 64), xb1 = __shfl(xb, 16+ch, 64);
    acc8_f32(aa, ab, ac, ad, xa0, xa1, acc0);
    acc8_f32(ba, bb, bc, bd, xb0, xb1, acc1);
  } else {
    const uint4* Ra = (const uint4*)((const u16*)g2 + pix*1024);
    const uint4* Rb = (const uint4*)((const u16*)g2 + (pix+1)*1024);
    uint4 a0 = ldnt_u4(Ra+l), a1 = ldnt_u4(Ra+64+l);
    uint4 b0 = ldnt_u4(Rb+l), b1 = ldnt_u4(Rb+64+l);
    float xa0 = __shfl(xa, ch, 64), xa1 = __shfl(xa, 16+ch, 64);
    float xb0 = __shfl(xb, ch, 64), xb1 = __shfl(xb, 16+ch, 64);
    acc8_bf(a0, a1, xa0, xa1, acc0);
    acc8_bf(b0, b1, xb0, xb1, acc1);
  }
  #pragma unroll
  for (int d = 4; d <= 32; d <<= 1){
    #pragma unroll
    for (int jj = 0; jj < 8; jj++){
      acc0[jj] += __shfl_xor(acc0[jj], d, 64);
      acc1[jj] += __shfl_xor(acc1[jj], d, 64);
    }
  }
  if (l < 4){
    ((float4*)(D + pix*32))[2*l]       = make_float4(acc0[0], acc0[1], acc0[2], acc0[3]);
    ((float4*)(D + pix*32))[2*l+1]     = make_float4(acc0[4], acc0[5], acc0[6], acc0[7]);
    ((float4*)(D + (pix+1)*32))[2*l]   = make_float4(acc1[0], acc1[1], acc1[2], acc1[3]);
    ((float4*)(D + (pix+1)*32))[2*l+1] = make_float4(acc1[4], acc1[5], acc1[6], acc1[7]);
  }
}

// ---- KG_A: per (p, j): B-combine + H-FFT + channel mix + H-IFFT ; 512 threads ----
__global__ __launch_bounds__(512) void kg_a(const float* S, const float* Dd, const float* tabs, float2* Q){
  __shared__ __align__(16) cpx E[64*128];   // 64 KB
  int t = threadIdx.x;
  int p = blockIdx.x >> 7, j = blockIdx.x & 127;
  const float* X = p ? Dd : S;
  const float* ampT = tabs + p*2048;
  const float* k0T  = ampT + 1024;
  int l = t & 63, w = t >> 6;               // w in [0,8)
  cpx tw[6]; make_tw(l, tw);

  // stage + combine over B: col c = (x0+x1) (B-freq 0), col 32+c = (x0-x1) (B-freq 1)
  {
    int h = t >> 2, ch = (t & 3) * 8;
    const float4* x0 = (const float4*)(X + (((size_t)h)*128 + j)*32 + ch);
    const float4* x1 = (const float4*)(X + (((size_t)(128 + h))*128 + j)*32 + ch);
    #pragma unroll
    for (int q = 0; q < 2; q++){
      float4 A = x0[q], B = x1[q];
      int c = ch + q*4;
      E[(c+0)*128 + h] = {A.x+B.x, 0.f};  E[(32+c+0)*128 + h] = {A.x-B.x, 0.f};
      E[(c+1)*128 + h] = {A.y+B.y, 0.f};  E[(32+c+1)*128 + h] = {A.y-B.y, 0.f};
      E[(c+2)*128 + h] = {A.z+B.z, 0.f};  E[(32+c+2)*128 + h] = {A.z-B.z, 0.f};
      E[(c+3)*128 + h] = {A.w+B.w, 0.f};  E[(32+c+3)*128 + h] = {A.w-B.w, 0.f};
    }
  }
  __syncthreads();
  // forward FFT over h for all 64 columns (bit-reversal folded into float4 store)
  for (int c = w; c < 64; c += 8){
    cpx* col = E + c*128;
    cpx v0 = col[l], v1 = col[l+64];
    fft_fwd(v0, v1, l, tw);
    ((float4*)col)[br6(l)] = make_float4(v0.x, v0.y, v1.x, v1.y);
  }
  __syncthreads();
  // mix: Y[b][o][i] = sum_c E[b][c][i] * G(c,o,i,j); G shared across b
  {
    int o = t & 31, ig = t >> 5;            // ig in [0,16)
    float aT[32], kT[32];
    #pragma unroll
    for (int c = 0; c < 32; c++){ aT[c] = ampT[c*32+o]; kT[c] = k0T[c*32+o]; }
    float fj = (j < 64) ? (float)j : (float)(j - 128);
    fj *= (PI2 / 128.0f);
    float px = fj * fj;
    for (int chunk = 0; chunk < 2; chunk++){
      cpx y0[4], y1[4];
      #pragma unroll
      for (int q = 0; q < 4; q++){
        int i = ig + 16*(chunk*4 + q);
        float fi = (i < 64) ? (float)i : (float)(i - 128);
        fi *= (PI2 / 128.0f);
        float pp = fmaf(fi, fi, px);
        cpx a0 = {0.f, 0.f}, a1 = {0.f, 0.f};
        #pragma unroll
        for (int c = 0; c < 32; c++){
          float dd  = fmaf(aT[c], pp, -kT[c]);
          float inv = __builtin_amdgcn_rcpf(fmaf(dd, dd, 1.0f));  // ~1ulp, << bf16 tol
          float gr = dd * inv, gi = inv;      // 1/(d - i) = (d + i)/(d^2+1)
          cpx x0 = E[c*128 + i];
          cpx x1 = E[(32+c)*128 + i];
          a0.x = fmaf(x0.x, gr, fmaf(-x0.y, gi, a0.x));
          a0.y = fmaf(x0.x, gi, fmaf( x0.y, gr, a0.y));
          a1.x = fmaf(x1.x, gr, fmaf(-x1.y, gi, a1.x));
          a1.y = fmaf(x1.x, gi, fmaf( x1.y, gr, a1.y));
        }
        y0[q] = a0; y1[q] = a1;
      }
      __syncthreads();
      #pragma unroll
      for (int q = 0; q < 4; q++){
        int i = ig + 16*(chunk*4 + q);
        E[o*128 + i]      = y0[q];
        E[(32+o)*128 + i] = y1[q];
      }
      __syncthreads();
    }
  }
  // inverse FFT over i for 64 (b,o) columns, scale 1/128
  for (int cidx = w; cidx < 64; cidx += 8){
    cpx* col = E + cidx*128;
    float4 tv = ((const float4*)col)[br6(l)];
    cpx v0 = {tv.x, tv.y}, v1 = {tv.z, tv.w};
    fft_inv(v0, v1, l, tw);
    const float sc = 1.0f/128.0f;
    col[l]    = {v0.x*sc, v0.y*sc};
    col[l+64] = {v1.x*sc, v1.y*sc};
  }
  __syncthreads();
  // writeout Q[p][b][y][j][o]
  {
    int o = t & 31, bb = (t >> 5) & 1, yb = t >> 6;   // yb in [0,8)
    for (int m = 0; m < 16; m++){
      int y = yb + 8*m;
      cpx v = E[(bb*32+o)*128 + y];
      Q[((((size_t)(p*2+bb))*128 + y)*128 + j)*32 + o] = make_float2(v.x, v.y);
    }
  }
}

// ---- KG_C: per (p, b, y): IFFT over W (natural input), real part -> G0/G1 [b][y][j][c] ----
// LDS strides padded: Z stride 130 cpx (16B-aligned cols, breaks 16-way write conflicts),
// R stride 133 floats (writeout gather conflict-free)
#define ZS 130
#define RS 133
__global__ __launch_bounds__(256) void kg_c(const float2* Q, float* G0, float* G1){
  __shared__ __align__(16) cpx Z[32*ZS];
  __shared__ float R[32*RS];
  int t = threadIdx.x, l = t & 63, w = t >> 6;
  int idx = blockIdx.x;
  int p = idx >> 8, rem = idx & 255, bb = rem >> 7, y = rem & 127;
  cpx tw[6]; make_tw(l, tw);
  const float4* src = (const float4*)(Q + ((size_t)((p*2+bb)*128 + y))*4096);
  for (int q = t; q < 2048; q += 256){
    float4 v = src[q];
    int m = q*2, jj = m >> 5, c = m & 31;
    Z[c*ZS + jj]     = {v.x, v.y};
    Z[(c+1)*ZS + jj] = {v.z, v.w};
  }
  __syncthreads();
  for (int c = w; c < 32; c += 4){
    cpx* col = Z + c*ZS;
    float4 tv = ((const float4*)col)[br6(l)];
    cpx v0 = {tv.x, tv.y}, v1 = {tv.z, tv.w};
    fft_inv(v0, v1, l, tw);
    R[c*RS + l]      = v0.x * (1.0f/128.0f);
    R[c*RS + l + 64] = v1.x * (1.0f/128.0f);
  }
  __syncthreads();
  float* dst = (p ? G1 : G0) + ((size_t)(bb*128 + y))*4096;
  int jj = t >> 3, c4 = (t & 7)*4;
  for (int rep = 0; rep < 4; rep++){
    int j2 = jj + rep*32;
    float4 o4 = { R[(c4+0)*RS + j2], R[(c4+1)*RS + j2],
                  R[(c4+2)*RS + j2], R[(c4+3)*RS + j2] };
    ((float4*)(dst + (size_t)j2*32))[c4 >> 2] = o4;
  }
}

// ---- K3: out = _D(g4,Gs) + _D(g1,Gm) + _D(g3,u) ; split grid, NT on g3 stream ----
__global__ __launch_bounds__(256) void k_final(const void* u, const void* g1, const void* g3, const void* g4,
    const float* G0, const float* G1, void* out, const int* flag, int pix0){
  int md = *flag;
  int t = threadIdx.x, l = t & 63;
  size_t pix = (size_t)pix0 + (size_t)blockIdx.x * 4 + (t >> 6);
  int c32 = l & 31, ch = l >> 2;
  float xs = G0[pix*32 + c32];
  float xm = G1[pix*32 + c32];
  float xu = ldv(u, pix*32 + c32, md);
  float acc[8] = {0.f,0.f,0.f,0.f,0.f,0.f,0.f,0.f};
  if (md){
    const float4* R4 = (const float4*)((const float*)g4 + pix*1024);
    const float4* R1 = (const float4*)((const float*)g1 + pix*1024);
    const float4* R3 = (const float4*)((const float*)g3 + pix*1024);
    float4 p4a = R4[2*l], p4b = R4[2*l+1], q4a = R4[128+2*l], q4b = R4[128+2*l+1];
    float4 p1a = R1[2*l], p1b = R1[2*l+1], q1a = R1[128+2*l], q1b = R1[128+2*l+1];
    float4 p3a = ldnt_f4(R3+2*l), p3b = ldnt_f4(R3+2*l+1), q3a = ldnt_f4(R3+128+2*l), q3b = ldnt_f4(R3+128+2*l+1);
    float xs0 = __shfl(xs, ch, 64), xs1 = __shfl(xs, 16+ch, 64);
    float xm0 = __shfl(xm, ch, 64), xm1 = __shfl(xm, 16+ch, 64);
    float xu0 = __shfl(xu, ch, 64), xu1 = __shfl(xu, 16+ch, 64);
    acc8_f32(p4a, p4b, q4a, q4b, xs0, xs1, acc);
    acc8_f32(p1a, p1b, q1a, q1b, xm0, xm1, acc);
    acc8_f32(p3a, p3b, q3a, q3b, xu0, xu1, acc);
  } else {
    const uint4* R4 = (const uint4*)((const u16*)g4 + pix*1024);
    const uint4* R1 = (const uint4*)((const u16*)g1 + pix*1024);
    const uint4* R3 = (const uint4*)((const u16*)g3 + pix*1024);
    uint4 a4 = R4[l], b4 = R4[64+l];
    uint4 a1 = R1[l], b1 = R1[64+l];
    uint4 a3 = ldnt_u4(R3+l), b3 = ldnt_u4(R3+64+l);
    float xs0 = __shfl(xs, ch, 64), xs1 = __shfl(xs, 16+ch, 64);
    float xm0 = __shfl(xm, ch, 64), xm1 = __shfl(xm, 16+ch, 64);
    float xu0 = __shfl(xu, ch, 64), xu1 = __shfl(xu, 16+ch, 64);
    acc8_bf(a4, b4, xs0, xs1, acc);
    acc8_bf(a1, b1, xm0, xm1, acc);
    acc8_bf(a3, b3, xu0, xu1, acc);
  }
  #pragma unroll
  for (int d = 4; d <= 32; d <<= 1){
    #pragma unroll
    for (int jj = 0; jj < 8; jj++) acc[jj] += __shfl_xor(acc[jj], d, 64);
  }
  if (l < 4){
    if (md){
      float4 o0 = {acc[0], acc[1], acc[2], acc[3]};
      float4 o1 = {acc[4], acc[5], acc[6], acc[7]};
      ((float4*)out)[pix*8 + 2*l]     = o0;
      ((float4*)out)[pix*8 + 2*l + 1] = o1;
    } else {
      uint4 v;
      v.x = (u32)f2bf(acc[0]) | ((u32)f2bf(acc[1]) << 16);
      v.y = (u32)f2bf(acc[2]) | ((u32)f2bf(acc[3]) << 16);
      v.z = (u32)f2bf(acc[4]) | ((u32)f2bf(acc[5]) << 16);
      v.w = (u32)f2bf(acc[6]) | ((u32)f2bf(acc[7]) << 16);
      ((uint4*)out)[pix*4 + l] = v;
    }
  }
}

extern "C" void kernel_launch(void* const* d_in, const int* in_sizes, int n_in,
                              void* d_out, int out_size, void* d_ws, size_t ws_size,
                              hipStream_t stream){
  (void)in_sizes; (void)n_in; (void)out_size; (void)ws_size;
  const void* u    = d_in[0];
  const void* kk   = d_in[1];
  const void* g1   = d_in[2];
  const void* g2   = d_in[3];
  const void* g3   = d_in[4];
  const void* g4   = d_in[5];
  const void* W1   = d_in[6];
  const void* b1   = d_in[7];
  const void* W2   = d_in[8];
  const void* b2   = d_in[9];
  const void* W3   = d_in[10];
  const void* b3   = d_in[11];
  const void* k0G  = d_in[12];
  const void* ampG = d_in[13];
  const void* k0Gs = d_in[14];
  const void* ampGs= d_in[15];

  float* ws   = (float*)d_ws;
  float* S    = ws;                          // 1M fp32
  float* Dd   = ws + (1u<<20);               // 1M fp32
  float2* Q   = (float2*)(ws + 2*(1u<<20));  // 2M cplx (4M fp32)
  float* G0   = ws + 6*(1u<<20);             // 1M fp32
  float* G1b  = ws + 7*(1u<<20);             // 1M fp32
  float* tabs = ws + 8*(1u<<20);             // 4K fp32
  int*   flag = (int*)(tabs + 4096);

  k_detect <<<1,    256, 0, stream>>>(g1, flag);
  k_tabs   <<<1,    256, 0, stream>>>(k0G, ampG, k0Gs, ampGs, tabs, flag);
  k_project<<<128,  256, 0, stream>>>(kk, W1, b1, W2, b2, W3, b3, S, flag);
  k_dmat   <<<4096, 256, 0, stream>>>(u, g2, Dd, flag);
  kg_a     <<<256,  512, 0, stream>>>(S, Dd, tabs, Q);
  kg_c     <<<512,  256, 0, stream>>>(Q, G0, G1b);
  k_final  <<<4096, 256, 0, stream>>>(u, g1, g3, g4, G0, G1b, (void*)d_out, flag, 0);
  k_final  <<<4096, 256, 0, stream>>>(u, g1, g3, g4, G0, G1b, (void*)d_out, flag, 16384);
}

// Round 5
// 533.070 us; speedup vs baseline: 1.0157x; 1.0110x over previous
//
#include <hip/hip_runtime.h>

using u16 = unsigned short;
using u32 = unsigned int;

#define PI2 6.283185307179586f

struct cpx { float x, y; };

typedef unsigned int uvec4 __attribute__((ext_vector_type(4)));
typedef float fvec4 __attribute__((ext_vector_type(4)));

__device__ __forceinline__ uint4 ldnt_u4(const uint4* p){
  uvec4 v = __builtin_nontemporal_load((const uvec4*)p);
  uint4 r; r.x = v.x; r.y = v.y; r.z = v.z; r.w = v.w; return r;
}
__device__ __forceinline__ float4 ldnt_f4(const float4* p){
  fvec4 v = __builtin_nontemporal_load((const fvec4*)p);
  float4 r; r.x = v.x; r.y = v.y; r.z = v.z; r.w = v.w; return r;
}

__device__ __forceinline__ float bf2f(u16 h){ return __uint_as_float(((u32)h) << 16); }
__device__ __forceinline__ u16 f2bf(float f){
  u32 u = __float_as_uint(f);
  u = u + 0x7fffu + ((u >> 16) & 1u);   // RNE
  return (u16)(u >> 16);
}

// mode: 0 = inputs/outputs bf16, 1 = fp32
__device__ __forceinline__ float ldv(const void* base, size_t i, int md){
  return md ? ((const float*)base)[i] : bf2f(((const u16*)base)[i]);
}

__device__ __forceinline__ cpx cadd(cpx a, cpx b){ return {a.x+b.x, a.y+b.y}; }
__device__ __forceinline__ cpx csub(cpx a, cpx b){ return {a.x-b.x, a.y-b.y}; }
__device__ __forceinline__ cpx cmul(cpx a, cpx b){ return {a.x*b.x - a.y*b.y, a.x*b.y + a.y*b.x}; }
__device__ __forceinline__ int br6(int l){ return (int)(__brev((u32)l) >> 26); }
__device__ __forceinline__ cpx shflx(cpx v, int m){
  cpx r; r.x = __shfl_xor(v.x, m, 64); r.y = __shfl_xor(v.y, m, 64); return r;
}

__device__ __forceinline__ void make_tw(int l, cpx tw[6]){
  #pragma unroll
  for (int s = 0; s < 6; s++){
    int h = 64 >> s;
    float ang = -PI2 * (float)(l & (h-1)) / (float)(2*h);
    float sv, cv; sincosf(ang, &sv, &cv);
    tw[s] = {cv, sv};
  }
}

// DIF, natural input (v0=pos l, v1=pos l+64); after float4 store at br6(l), natural order
__device__ __forceinline__ void fft_fwd(cpx& v0, cpx& v1, int l, const cpx tw[6]){
  cpx a = cadd(v0, v1), b = csub(v0, v1);
  v0 = a; v1 = cmul(b, tw[0]);
  #pragma unroll
  for (int s = 1; s < 6; s++){
    int h = 64 >> s;
    cpx p0 = shflx(v0, h), p1 = shflx(v1, h);
    bool up = (l & h) != 0;
    cpx n0 = up ? cmul(csub(p0, v0), tw[s]) : cadd(v0, p0);
    cpx n1 = up ? cmul(csub(p1, v1), tw[s]) : cadd(v1, p1);
    v0 = n0; v1 = n1;
  }
  { cpx p0 = shflx(v0, 1), p1 = shflx(v1, 1);
    bool up = (l & 1) != 0;
    v0 = up ? csub(p0, v0) : cadd(v0, p0);
    v1 = up ? csub(p1, v1) : cadd(v1, p1); }
}

// DIT, input gathered via float4 at br6(l) from natural order; unnormalized IDFT
__device__ __forceinline__ void fft_inv(cpx& v0, cpx& v1, int l, const cpx tw[6]){
  { cpx p0 = shflx(v0, 1), p1 = shflx(v1, 1);
    bool up = (l & 1) != 0;
    v0 = up ? csub(p0, v0) : cadd(v0, p0);
    v1 = up ? csub(p1, v1) : cadd(v1, p1); }
  #pragma unroll
  for (int s = 5; s >= 1; s--){
    int h = 64 >> s;
    cpx twc = {tw[s].x, -tw[s].y};
    cpx p0 = shflx(v0, h), p1 = shflx(v1, h);
    bool up = (l & h) != 0;
    cpx t0 = cmul(up ? v0 : p0, twc);
    cpx t1 = cmul(up ? v1 : p1, twc);
    v0 = up ? csub(p0, t0) : cadd(v0, t0);
    v1 = up ? csub(p1, t1) : cadd(v1, t1);
  }
  { cpx twc = {tw[0].x, -tw[0].y};
    cpx t = cmul(v1, twc);
    cpx n0 = cadd(v0, t), n1 = csub(v0, t);
    v0 = n0; v1 = n1; }
}

__device__ __forceinline__ float softplusf(float x){ return (x > 20.0f) ? x : log1pf(expf(x)); }

// ---- contiguous-row matvec helpers ----
__device__ __forceinline__ void acc8_bf(uint4 a, uint4 b, float x0, float x1, float acc[8]){
  acc[0] = fmaf(x0, __uint_as_float(a.x << 16),         acc[0]);
  acc[1] = fmaf(x0, __uint_as_float(a.x & 0xffff0000u), acc[1]);
  acc[2] = fmaf(x0, __uint_as_float(a.y << 16),         acc[2]);
  acc[3] = fmaf(x0, __uint_as_float(a.y & 0xffff0000u), acc[3]);
  acc[4] = fmaf(x0, __uint_as_float(a.z << 16),         acc[4]);
  acc[5] = fmaf(x0, __uint_as_float(a.z & 0xffff0000u), acc[5]);
  acc[6] = fmaf(x0, __uint_as_float(a.w << 16),         acc[6]);
  acc[7] = fmaf(x0, __uint_as_float(a.w & 0xffff0000u), acc[7]);
  acc[0] = fmaf(x1, __uint_as_float(b.x << 16),         acc[0]);
  acc[1] = fmaf(x1, __uint_as_float(b.x & 0xffff0000u), acc[1]);
  acc[2] = fmaf(x1, __uint_as_float(b.y << 16),         acc[2]);
  acc[3] = fmaf(x1, __uint_as_float(b.y & 0xffff0000u), acc[3]);
  acc[4] = fmaf(x1, __uint_as_float(b.z << 16),         acc[4]);
  acc[5] = fmaf(x1, __uint_as_float(b.z & 0xffff0000u), acc[5]);
  acc[6] = fmaf(x1, __uint_as_float(b.w << 16),         acc[6]);
  acc[7] = fmaf(x1, __uint_as_float(b.w & 0xffff0000u), acc[7]);
}
__device__ __forceinline__ void acc8_f32(float4 a0, float4 a1, float4 b0, float4 b1,
                                         float x0, float x1, float acc[8]){
  acc[0] = fmaf(x0, a0.x, acc[0]); acc[1] = fmaf(x0, a0.y, acc[1]);
  acc[2] = fmaf(x0, a0.z, acc[2]); acc[3] = fmaf(x0, a0.w, acc[3]);
  acc[4] = fmaf(x0, a1.x, acc[4]); acc[5] = fmaf(x0, a1.y, acc[5]);
  acc[6] = fmaf(x0, a1.z, acc[6]); acc[7] = fmaf(x0, a1.w, acc[7]);
  acc[0] = fmaf(x1, b0.x, acc[0]); acc[1] = fmaf(x1, b0.y, acc[1]);
  acc[2] = fmaf(x1, b0.z, acc[2]); acc[3] = fmaf(x1, b0.w, acc[3]);
  acc[4] = fmaf(x1, b1.x, acc[4]); acc[5] = fmaf(x1, b1.y, acc[5]);
  acc[6] = fmaf(x1, b1.z, acc[6]); acc[7] = fmaf(x1, b1.w, acc[7]);
}

// ---- K_DETECT: sample g1 as bf16; fp32 low-halves look huge/NaN -> mode 1 ----
__global__ void k_detect(const void* g1, int* flag){
  __shared__ int cnt;
  if (threadIdx.x == 0) cnt = 0;
  __syncthreads();
  const u16* p = (const u16*)g1;
  int local = 0;
  for (int i = threadIdx.x; i < 4096; i += 256){
    float v = bf2f(p[i]);
    if (!(fabsf(v) < 100.0f)) local++;   // counts NaN/inf too
  }
  atomicAdd(&cnt, local);
  __syncthreads();
  if (threadIdx.x == 0) *flag = (cnt > 64) ? 1 : 0;
}

// ---- K0: softplus tables: [amp_Gs, k0_Gs, amp_G, k0_G], 1024 fp32 each ----
__global__ void k_tabs(const void* k0G, const void* ampG, const void* k0Gs, const void* ampGs,
                       float* tabs, const int* flag){
  int md = *flag;
  for (int i = threadIdx.x; i < 1024; i += 256){
    tabs[i]        = softplusf(ldv(ampGs, i, md));
    tabs[1024 + i] = softplusf(ldv(k0Gs, i, md));
    tabs[2048 + i] = softplusf(ldv(ampG, i, md));
    tabs[3072 + i] = softplusf(ldv(k0G, i, md));
  }
}

// ---- K1: per-pixel MLP s = project(k) -> S[b][h][j][c] fp32 ----
__global__ __launch_bounds__(256) void k_project(const void* kin, const void* W1, const void* b1,
    const void* W2, const void* b2, const void* W3, const void* b3, float* S, const int* flag){
  __shared__ float sW2[1024], sW3[1024], sml[128];
  int md = *flag;
  int t = threadIdx.x;
  for (int i = t; i < 1024; i += 256){ sW2[i] = ldv(W2, i, md); sW3[i] = ldv(W3, i, md); }
  if (t < 32){
    sml[t]     = ldv(W1, t, md); sml[32+t] = ldv(b1, t, md);
    sml[64+t]  = ldv(b2, t, md); sml[96+t] = ldv(b3, t, md);
  }
  __syncthreads();
  int pix = blockIdx.x * 256 + t;
  float kv = ldv(kin, pix, md);
  float a1[32], a2[32];
  #pragma unroll
  for (int c = 0; c < 32; c++){ float z = fmaf(kv, sml[c], sml[32+c]); a1[c] = expf(-z*z); }
  for (int o = 0; o < 32; o++){
    float z = sml[64+o];
    #pragma unroll
    for (int c = 0; c < 32; c++) z = fmaf(a1[c], sW2[c*32+o], z);
    a2[o] = expf(-z*z);
  }
  for (int o = 0; o < 32; o++){
    float sv = sml[96+o];
    #pragma unroll
    for (int c = 0; c < 32; c++) sv = fmaf(a2[c], sW3[c*32+o], sv);
    S[(size_t)pix*32 + o] = sv;
  }
}

// ---- K2: Du = _D(g2, u) -> fp32 ; 1 wave = 2 pixels, NT streaming g2 reads ----
__global__ __launch_bounds__(256) void k_dmat(const void* u, const void* g2, float* D, const int* flag){
  int md = *flag;
  int t = threadIdx.x, l = t & 63;
  size_t pix = (size_t)blockIdx.x * 8 + (size_t)(t >> 6) * 2;
  int c32 = l & 31, ch = l >> 2;
  float xa = ldv(u, pix*32 + c32, md);
  float xb = ldv(u, (pix+1)*32 + c32, md);
  float acc0[8] = {0.f,0.f,0.f,0.f,0.f,0.f,0.f,0.f};
  float acc1[8] = {0.f,0.f,0.f,0.f,0.f,0.f,0.f,0.f};
  if (md){
    const float4* Ra = (const float4*)((const float*)g2 + pix*1024);
    const float4* Rb = (const float4*)((const float*)g2 + (pix+1)*1024);
    float4 aa = ldnt_f4(Ra+2*l), ab = ldnt_f4(Ra+2*l+1), ac = ldnt_f4(Ra+128+2*l), ad = ldnt_f4(Ra+128+2*l+1);
    float4 ba = ldnt_f4(Rb+2*l), bb = ldnt_f4(Rb+2*l+1), bc = ldnt_f4(Rb+128+2*l), bd = ldnt_f4(Rb+128+2*l+1);
    float xa0 = __shfl(xa, ch, 64), xa1 = __shfl(xa, 16+ch, 64);
    float xb0 = __shfl(xb, ch, 64), xb1 = __shfl(xb, 16+ch, 64);
    acc8_f32(aa, ab, ac, ad, xa0, xa1, acc0);
    acc8_f32(ba, bb, bc, bd, xb0, xb1, acc1);
  } else {
    const uint4* Ra = (const uint4*)((const u16*)g2 + pix*1024);
    const uint4* Rb = (const uint4*)((const u16*)g2 + (pix+1)*1024);
    uint4 a0 = ldnt_u4(Ra+l), a1 = ldnt_u4(Ra+64+l);
    uint4 b0 = ldnt_u4(Rb+l), b1 = ldnt_u4(Rb+64+l);
    float xa0 = __shfl(xa, ch, 64), xa1 = __shfl(xa, 16+ch, 64);
    float xb0 = __shfl(xb, ch, 64), xb1 = __shfl(xb, 16+ch, 64);
    acc8_bf(a0, a1, xa0, xa1, acc0);
    acc8_bf(b0, b1, xb0, xb1, acc1);
  }
  #pragma unroll
  for (int d = 4; d <= 32; d <<= 1){
    #pragma unroll
    for (int jj = 0; jj < 8; jj++){
      acc0[jj] += __shfl_xor(acc0[jj], d, 64);
      acc1[jj] += __shfl_xor(acc1[jj], d, 64);
    }
  }
  if (l < 4){
    ((float4*)(D + pix*32))[2*l]       = make_float4(acc0[0], acc0[1], acc0[2], acc0[3]);
    ((float4*)(D + pix*32))[2*l+1]     = make_float4(acc0[4], acc0[5], acc0[6], acc0[7]);
    ((float4*)(D + (pix+1)*32))[2*l]   = make_float4(acc1[0], acc1[1], acc1[2], acc1[3]);
    ((float4*)(D + (pix+1)*32))[2*l+1] = make_float4(acc1[4], acc1[5], acc1[6], acc1[7]);
  }
}

// ---- KG_A: per (p, j, b): B-combine + H-FFT + channel mix + H-IFFT ----
// split by B-frequency b (independent after combine); 256 thr, 32 cols, ES=130 pad
#define ES 130
__global__ __launch_bounds__(256) void kg_a(const float* S, const float* Dd, const float* tabs, float2* Q){
  __shared__ __align__(16) cpx E[32*ES];   // ~33 KB
  int t = threadIdx.x;
  int bid = blockIdx.x;
  int p = bid >> 8, b = (bid >> 7) & 1, j = bid & 127;
  const float* X = p ? Dd : S;
  const float* ampT = tabs + p*2048;
  const float* k0T  = ampT + 1024;
  int l = t & 63, w = t >> 6;               // w in [0,4)
  cpx tw[6]; make_tw(l, tw);

  // stage + combine over B: E[c][h] = x0[c] + sgn*x1[c]
  {
    int h = t >> 1, ch = (t & 1) * 16;
    const float4* x0 = (const float4*)(X + (((size_t)h)*128 + j)*32 + ch);
    const float4* x1 = (const float4*)(X + (((size_t)(128 + h))*128 + j)*32 + ch);
    float sgn = b ? -1.f : 1.f;
    #pragma unroll
    for (int q = 0; q < 4; q++){
      float4 A = x0[q], B = x1[q];
      int c = ch + q*4;
      E[(c+0)*ES + h] = {fmaf(sgn, B.x, A.x), 0.f};
      E[(c+1)*ES + h] = {fmaf(sgn, B.y, A.y), 0.f};
      E[(c+2)*ES + h] = {fmaf(sgn, B.z, A.z), 0.f};
      E[(c+3)*ES + h] = {fmaf(sgn, B.w, A.w), 0.f};
    }
  }
  __syncthreads();
  // forward FFT over h for 32 columns (bit-reversal folded into float4 store)
  for (int c = w; c < 32; c += 4){
    cpx* col = E + c*ES;
    cpx v0 = col[l], v1 = col[l+64];
    fft_fwd(v0, v1, l, tw);
    ((float4*)col)[br6(l)] = make_float4(v0.x, v0.y, v1.x, v1.y);
  }
  __syncthreads();
  // mix: Y[o][i] = sum_c E[c][i] * G(c,o,i,j)
  {
    int o = t & 31, ig = t >> 5;            // ig in [0,8)
    float aT[32], kT[32];
    #pragma unroll
    for (int c = 0; c < 32; c++){ aT[c] = ampT[c*32+o]; kT[c] = k0T[c*32+o]; }
    float fj = (j < 64) ? (float)j : (float)(j - 128);
    fj *= (PI2 / 128.0f);
    float px = fj * fj;
    for (int chunk = 0; chunk < 4; chunk++){
      cpx y0[4];
      #pragma unroll
      for (int q = 0; q < 4; q++){
        int i = ig + 8*(chunk*4 + q);
        float fi = (i < 64) ? (float)i : (float)(i - 128);
        fi *= (PI2 / 128.0f);
        float pp = fmaf(fi, fi, px);
        cpx a0 = {0.f, 0.f};
        #pragma unroll
        for (int c = 0; c < 32; c++){
          float dd  = fmaf(aT[c], pp, -kT[c]);
          float inv = __builtin_amdgcn_rcpf(fmaf(dd, dd, 1.0f));  // ~1ulp, << bf16 tol
          float gr = dd * inv, gi = inv;      // 1/(d - i) = (d + i)/(d^2+1)
          cpx x0 = E[c*ES + i];
          a0.x = fmaf(x0.x, gr, fmaf(-x0.y, gi, a0.x));
          a0.y = fmaf(x0.x, gi, fmaf( x0.y, gr, a0.y));
        }
        y0[q] = a0;
      }
      __syncthreads();
      #pragma unroll
      for (int q = 0; q < 4; q++){
        int i = ig + 8*(chunk*4 + q);
        E[o*ES + i] = y0[q];
      }
      __syncthreads();
    }
  }
  // inverse FFT over i for 32 (o) columns, scale 1/128
  for (int cidx = w; cidx < 32; cidx += 4){
    cpx* col = E + cidx*ES;
    float4 tv = ((const float4*)col)[br6(l)];
    cpx v0 = {tv.x, tv.y}, v1 = {tv.z, tv.w};
    fft_inv(v0, v1, l, tw);
    const float sc = 1.0f/128.0f;
    col[l]    = {v0.x*sc, v0.y*sc};
    col[l+64] = {v1.x*sc, v1.y*sc};
  }
  __syncthreads();
  // writeout Q[p][b][y][j][o]
  {
    int o = t & 31, yb = t >> 5;   // yb in [0,8)
    for (int m = 0; m < 16; m++){
      int y = yb + 8*m;
      cpx v = E[o*ES + y];
      Q[((((size_t)(p*2+b))*128 + y)*128 + j)*32 + o] = make_float2(v.x, v.y);
    }
  }
}

// ---- KG_C: per (p, b, y, h): IFFT over W for 16 channels, real part -> G0/G1 ----
// split by channel half h; LDS strides padded (ZS=130 cpx, RS=133 f)
#define ZS 130
#define RS 133
__global__ __launch_bounds__(256) void kg_c(const float2* Q, float* G0, float* G1){
  __shared__ __align__(16) cpx Z[16*ZS];
  __shared__ float R[16*RS];
  int t = threadIdx.x, l = t & 63, w = t >> 6;
  int idx = blockIdx.x;
  int p = idx >> 9, rem = idx & 511, bb = rem >> 8, y = (rem >> 1) & 127, h = rem & 1;
  cpx tw[6]; make_tw(l, tw);
  const float4* src = (const float4*)(Q + ((size_t)((p*2+bb)*128 + y))*4096);
  for (int i = t; i < 1024; i += 256){
    int q = (i >> 3)*16 + 8*h + (i & 7);
    float4 v = src[q];
    int m = q*2, jj = m >> 5, cl = (m & 31) - 16*h;
    Z[cl*ZS + jj]     = {v.x, v.y};
    Z[(cl+1)*ZS + jj] = {v.z, v.w};
  }
  __syncthreads();
  for (int cl = w; cl < 16; cl += 4){
    cpx* col = Z + cl*ZS;
    float4 tv = ((const float4*)col)[br6(l)];
    cpx v0 = {tv.x, tv.y}, v1 = {tv.z, tv.w};
    fft_inv(v0, v1, l, tw);
    R[cl*RS + l]      = v0.x * (1.0f/128.0f);
    R[cl*RS + l + 64] = v1.x * (1.0f/128.0f);
  }
  __syncthreads();
  float* dst = (p ? G1 : G0) + ((size_t)(bb*128 + y))*4096;
  int jj = t >> 2, c4 = (t & 3)*4;
  for (int rep = 0; rep < 2; rep++){
    int j2 = jj + rep*64;
    float4 o4 = { R[(c4+0)*RS + j2], R[(c4+1)*RS + j2],
                  R[(c4+2)*RS + j2], R[(c4+3)*RS + j2] };
    ((float4*)(dst + (size_t)j2*32 + 16*h))[c4 >> 2] = o4;
  }
}

// ---- K3: out = _D(g4,Gs) + _D(g1,Gm) + _D(g3,u) ; split grid, NT on g3 stream ----
__global__ __launch_bounds__(256) void k_final(const void* u, const void* g1, const void* g3, const void* g4,
    const float* G0, const float* G1, void* out, const int* flag, int pix0){
  int md = *flag;
  int t = threadIdx.x, l = t & 63;
  size_t pix = (size_t)pix0 + (size_t)blockIdx.x * 4 + (t >> 6);
  int c32 = l & 31, ch = l >> 2;
  float xs = G0[pix*32 + c32];
  float xm = G1[pix*32 + c32];
  float xu = ldv(u, pix*32 + c32, md);
  float acc[8] = {0.f,0.f,0.f,0.f,0.f,0.f,0.f,0.f};
  if (md){
    const float4* R4 = (const float4*)((const float*)g4 + pix*1024);
    const float4* R1 = (const float4*)((const float*)g1 + pix*1024);
    const float4* R3 = (const float4*)((const float*)g3 + pix*1024);
    float4 p4a = R4[2*l], p4b = R4[2*l+1], q4a = R4[128+2*l], q4b = R4[128+2*l+1];
    float4 p1a = R1[2*l], p1b = R1[2*l+1], q1a = R1[128+2*l], q1b = R1[128+2*l+1];
    float4 p3a = ldnt_f4(R3+2*l), p3b = ldnt_f4(R3+2*l+1), q3a = ldnt_f4(R3+128+2*l), q3b = ldnt_f4(R3+128+2*l+1);
    float xs0 = __shfl(xs, ch, 64), xs1 = __shfl(xs, 16+ch, 64);
    float xm0 = __shfl(xm, ch, 64), xm1 = __shfl(xm, 16+ch, 64);
    float xu0 = __shfl(xu, ch, 64), xu1 = __shfl(xu, 16+ch, 64);
    acc8_f32(p4a, p4b, q4a, q4b, xs0, xs1, acc);
    acc8_f32(p1a, p1b, q1a, q1b, xm0, xm1, acc);
    acc8_f32(p3a, p3b, q3a, q3b, xu0, xu1, acc);
  } else {
    const uint4* R4 = (const uint4*)((const u16*)g4 + pix*1024);
    const uint4* R1 = (const uint4*)((const u16*)g1 + pix*1024);
    const uint4* R3 = (const uint4*)((const u16*)g3 + pix*1024);
    uint4 a4 = R4[l], b4 = R4[64+l];
    uint4 a1 = R1[l], b1 = R1[64+l];
    uint4 a3 = ldnt_u4(R3+l), b3 = ldnt_u4(R3+64+l);
    float xs0 = __shfl(xs, ch, 64), xs1 = __shfl(xs, 16+ch, 64);
    float xm0 = __shfl(xm, ch, 64), xm1 = __shfl(xm, 16+ch, 64);
    float xu0 = __shfl(xu, ch, 64), xu1 = __shfl(xu, 16+ch, 64);
    acc8_bf(a4, b4, xs0, xs1, acc);
    acc8_bf(a1, b1, xm0, xm1, acc);
    acc8_bf(a3, b3, xu0, xu1, acc);
  }
  #pragma unroll
  for (int d = 4; d <= 32; d <<= 1){
    #pragma unroll
    for (int jj = 0; jj < 8; jj++) acc[jj] += __shfl_xor(acc[jj], d, 64);
  }
  if (l < 4){
    if (md){
      float4 o0 = {acc[0], acc[1], acc[2], acc[3]};
      float4 o1 = {acc[4], acc[5], acc[6], acc[7]};
      ((float4*)out)[pix*8 + 2*l]     = o0;
      ((float4*)out)[pix*8 + 2*l + 1] = o1;
    } else {
      uint4 v;
      v.x = (u32)f2bf(acc[0]) | ((u32)f2bf(acc[1]) << 16);
      v.y = (u32)f2bf(acc[2]) | ((u32)f2bf(acc[3]) << 16);
      v.z = (u32)f2bf(acc[4]) | ((u32)f2bf(acc[5]) << 16);
      v.w = (u32)f2bf(acc[6]) | ((u32)f2bf(acc[7]) << 16);
      ((uint4*)out)[pix*4 + l] = v;
    }
  }
}

extern "C" void kernel_launch(void* const* d_in, const int* in_sizes, int n_in,
                              void* d_out, int out_size, void* d_ws, size_t ws_size,
                              hipStream_t stream){
  (void)in_sizes; (void)n_in; (void)out_size; (void)ws_size;
  const void* u    = d_in[0];
  const void* kk   = d_in[1];
  const void* g1   = d_in[2];
  const void* g2   = d_in[3];
  const void* g3   = d_in[4];
  const void* g4   = d_in[5];
  const void* W1   = d_in[6];
  const void* b1   = d_in[7];
  const void* W2   = d_in[8];
  const void* b2   = d_in[9];
  const void* W3   = d_in[10];
  const void* b3   = d_in[11];
  const void* k0G  = d_in[12];
  const void* ampG = d_in[13];
  const void* k0Gs = d_in[14];
  const void* ampGs= d_in[15];

  float* ws   = (float*)d_ws;
  float* S    = ws;                          // 1M fp32
  float* Dd   = ws + (1u<<20);               // 1M fp32
  float2* Q   = (float2*)(ws + 2*(1u<<20));  // 2M cplx (4M fp32)
  float* G0   = ws + 6*(1u<<20);             // 1M fp32
  float* G1b  = ws + 7*(1u<<20);             // 1M fp32
  float* tabs = ws + 8*(1u<<20);             // 4K fp32
  int*   flag = (int*)(tabs + 4096);

  k_detect <<<1,    256, 0, stream>>>(g1, flag);
  k_tabs   <<<1,    256, 0, stream>>>(k0G, ampG, k0Gs, ampGs, tabs, flag);
  k_project<<<128,  256, 0, stream>>>(kk, W1, b1, W2, b2, W3, b3, S, flag);
  k_dmat   <<<4096, 256, 0, stream>>>(u, g2, Dd, flag);
  kg_a     <<<512,  256, 0, stream>>>(S, Dd, tabs, Q);
  kg_c     <<<1024, 256, 0, stream>>>(Q, G0, G1b);
  k_final  <<<4096, 256, 0, stream>>>(u, g1, g3, g4, G0, G1b, (void*)d_out, flag, 0);
  k_final  <<<4096, 256, 0, stream>>>(u, g1, g3, g4, G0, G1b, (void*)d_out, flag, 16384);
}